// Round 10
// baseline (131.965 us; speedup 1.0000x reference)
//
#include <hip/hip_runtime.h>
#include <hip/hip_bf16.h>
#include <hip/hip_cooperative_groups.h>

// Poly2d as bf16 MFMA GEMM, register-resident Q. Single cooperative dispatch:
// phase A builds W2 (symmetrized/permuted filters) in d_ws, grid.sync(),
// phase B = R9's verified GEMM body.
//
// out[o,p] = sum_{c,kl} W[o,c,kl] * Q[c,kl,p], kl in [0,56):
//   kl 0..8 linear (s_j*(F0j+Fj0)), 9..17 squares (s_j^2*Fjj),
//   18..53 pairs (s_i*s_j*(Fij+Fji)), 54 const-1 (F00 + bias @c==0), 55 zero.
// MFMA 32x32x16 B-operand: lane (hf=l>>5, n=l&31) holds B[k=hf*8+e][n].
// k-slot -> (channel,kl) bijection so each lane's slots use only channels
// cA = 2*pair+hf, cB = 2*pair+1-hf with compile-time kl:
//   step st<4 : ch = cA, kl = 16*st + e
//   step st>=4: ch = cB, kl = 16*(st-4)+8+e
// W2 layout: pair*7168 + st*1024 + hf*512 + o*8 + e (shorts).

namespace cg = cooperative_groups;

typedef __attribute__((ext_vector_type(8))) short short8;
typedef __attribute__((ext_vector_type(16))) float f32x16;

#define NCH  64
#define NOUT 64

__device__ constexpr signed char TI[56] = {
  0,0,0,0,0,0,0,0,0,
  1,2,3,4,5,6,7,8,9,
  1,1,1,1,1,1,1,1,
  2,2,2,2,2,2,2,
  3,3,3,3,3,3,
  4,4,4,4,4,
  5,5,5,5,
  6,6,6,
  7,7,
  8,
  0,0};
__device__ constexpr signed char TJ[56] = {
  1,2,3,4,5,6,7,8,9,
  1,2,3,4,5,6,7,8,9,
  2,3,4,5,6,7,8,9,
  3,4,5,6,7,8,9,
  4,5,6,7,8,9,
  5,6,7,8,9,
  6,7,8,9,
  7,8,9,
  8,9,
  9,
  0,0};

__device__ __forceinline__ unsigned short f2bf(float f) {
  __hip_bfloat16 h = __float2bfloat16(f);
  unsigned short u;
  __builtin_memcpy(&u, &h, 2);
  return u;
}

// 256 blocks = (b, h); 1024 threads = 16 waves = (kg 0..7, ph 0..1).
// Phase A: block (pair = bid>>3, og = bid&7) builds its W2 slice (proven
//   prep_w2 v3.1 mapping, single-shot with 1024 threads).
// Phase B: wave (kg,ph): channels [8kg,8kg+8), pixels [32ph,32ph+32),
//   o 0..63 (2 acc tiles). LDS arena 139 KB (Fl 6.4 KB / xs 55 KB /
//   reduction 139 KB, phase-aliased): 1 block/CU, 4 waves/SIMD @ <=128 VGPR.
__global__ __launch_bounds__(1024, 4) void poly2d_fused(
    const float* __restrict__ x, unsigned short* __restrict__ W2,
    const float* __restrict__ F, const float* __restrict__ biases,
    float* __restrict__ out) {
  const int tid = threadIdx.x;
  __shared__ float smem[34816];   // 139264 B

  // ================= phase A: build W2 slice (pair, og) =================
  {
    const int pair = blockIdx.x >> 3, og = blockIdx.x & 7;
    float* Fl = smem;             // [o8][chl*100 + i*10+j], 1600 floats
    float* bl = smem + 1600;
    if (tid < 400) {              // 400 float4 = 1600 floats, coalesced
      int o8 = tid / 50, r = tid % 50;
      *(float4*)&Fl[o8 * 200 + r * 4] =
          *(const float4*)&F[(((size_t)(og * 8 + o8)) * NCH + 2 * pair) * 100 + r * 4];
    }
    if (tid < 8) bl[tid] = biases[og * 8 + tid];
    __syncthreads();
    if (tid < 112) {              // o8 fast -> 8 consecutive short8 = 128B
      int o8 = tid & 7, hf = (tid >> 3) & 1, st = tid >> 4;
      int chl = (st < 4) ? hf : 1 - hf;
      const float* base = &Fl[o8 * 200 + chl * 100];
      short8 v;
      #pragma unroll
      for (int e = 0; e < 8; ++e) {
        int kl = (st < 4) ? (16 * st + e) : (16 * (st - 4) + 8 + e);
        float w;
        if (kl < 54) {
          int i = TI[kl], j = TJ[kl];
          if (i == 0)      w = base[j] + base[j * 10];
          else if (i == j) w = base[i * 10 + j];
          else             w = base[i * 10 + j] + base[j * 10 + i];
        } else if (kl == 54) {
          w = base[0] + ((pair == 0 && chl == 0) ? bl[o8] : 0.f);
        } else {
          w = 0.f;
        }
        v[e] = (short)f2bf(w);
      }
      *(short8*)&W2[(size_t)pair * 7168 + (size_t)st * 1024 + hf * 512 +
                    (og * 8 + o8) * 8] = v;
    }
  }
  __threadfence();                // agent-scope release (L2 writeback)
  cg::this_grid().sync();         // W2 complete & visible device-wide

  // ================= phase B: GEMM (R9 verified body) =================
  const int b = blockIdx.x >> 6, h = blockIdx.x & 63;
  const int lane = tid & 63, wid = tid >> 6;
  const int kg = wid >> 1, ph = wid & 1;
  const int px = lane & 31, hf = lane >> 5;
  const int pxa = ph * 32 + px;            // this wave's absolute pixel

  // ---- stage: wave wid stages channels [4*wid, 4*wid+4) ----
  {
    const int r = lane >> 4, q = lane & 15;          // lanes 0..47: body quads
    const size_t xbase = ((size_t)b * NCH + wid * 4) * 4096;
    #pragma unroll
    for (int i = 0; i < 4; ++i) {
      float* ch0 = &smem[(wid * 4 + i) * 216];
      if (lane < 48) {
        int hh = h + r - 1;
        bool ok = (unsigned)hh < 64u;
        int hcl = ok ? hh : 0;                       // clamped (safe) address
        float4 v = *(const float4*)&x[xbase + (size_t)i * 4096 + hcl * 64 + (q << 2)];
        if (!ok) v = make_float4(0.f, 0.f, 0.f, 0.f);
        *(float4*)&ch0[r * 72 + 4 + (q << 2)] = v;
      } else if (lane < 54) {
        int rr = (lane - 48) >> 1, side = lane & 1;  // zero halo cols
        *(float4*)&ch0[rr * 72 + (side ? 68 : 0)] = make_float4(0.f, 0.f, 0.f, 0.f);
      }
    }
  }
  __syncthreads();                 // staging shared across waves

  f32x16 acc0, acc1;               // o 0..31 / o 32..63 at this wave's px
  #pragma unroll
  for (int r = 0; r < 16; ++r) { acc0[r] = 0.f; acc1[r] = 0.f; }

  #pragma unroll
  for (int stage = 0; stage < 4; ++stage) {
    const int cA = kg * 8 + stage * 2 + hf;   // channel of this lane-half
    const int cB = cA ^ 1;

    const float* rA = &smem[cA * 216 + pxa];
    const float* rB = &smem[cB * 216 + pxa];
    float sa[9], sb[9];
    #pragma unroll
    for (int r = 0; r < 3; ++r)
      #pragma unroll
      for (int d = 0; d < 3; ++d) {
        sa[r * 3 + d] = rA[r * 72 + 3 + d];
        sb[r * 3 + d] = rB[r * 72 + 3 + d];
      }

    const unsigned short* wb = W2 + (size_t)(kg * 4 + stage) * 7168 +
                               hf * 512 + px * 8;
    #pragma unroll
    for (int st = 0; st < 7; ++st) {
      const short8 w0 = *(const short8*)(wb + st * 1024);        // o 0..31
      const short8 w1 = *(const short8*)(wb + st * 1024 + 256);  // o 32..63
      short8 pk;
      #pragma unroll
      for (int e = 0; e < 8; ++e) {
        const int kl = (st < 4) ? (16 * st + e) : (16 * (st - 4) + 8 + e);
        const float* s = (st < 4) ? sa : sb;
        float v;
        if (kl == 55)      v = 0.f;
        else if (kl == 54) v = 1.f;
        else if (kl < 9)   v = s[kl];
        else if (kl < 18)  { float t = s[kl - 9]; v = t * t; }
        else               v = s[TI[kl] - 1] * s[TJ[kl] - 1];
        pk[e] = (short)f2bf(v);
      }
      acc0 = __builtin_amdgcn_mfma_f32_32x32x16_bf16(w0, pk, acc0, 0, 0, 0);
      acc1 = __builtin_amdgcn_mfma_f32_32x32x16_bf16(w1, pk, acc1, 0, 0, 0);
    }
  }

  // ---- single-round reduction over the 8 kg partials ----
  __syncthreads();               // all waves done with xs (arena reused as R)
  // D layout (m74/m101): col = lane&31 (= pixel), row = (r&3)+8*(r>>2)+4*hf
  // (= o_local). R(kg, p, o) at smem[(kg*64+p)*68 + o].
  {
    float* base = &smem[(kg * 64 + pxa) * 68];
    #pragma unroll
    for (int blk = 0; blk < 4; ++blk) {
      int ob = blk * 8 + 4 * hf;
      *(float4*)&base[ob]      = make_float4(acc0[blk*4], acc0[blk*4+1], acc0[blk*4+2], acc0[blk*4+3]);
      *(float4*)&base[ob + 32] = make_float4(acc1[blk*4], acc1[blk*4+1], acc1[blk*4+2], acc1[blk*4+3]);
    }
  }
  __syncthreads();
  {
    const int p = tid & 63, oq = tid >> 6;   // o-quad 0..15
    float4 sum = make_float4(0.f, 0.f, 0.f, 0.f);
    #pragma unroll
    for (int g = 0; g < 8; ++g) {
      float4 v = *(const float4*)&smem[(g * 64 + p) * 68 + oq * 4];
      sum.x += v.x; sum.y += v.y; sum.z += v.z; sum.w += v.w;
    }
    const size_t obase = (((size_t)b * NOUT + oq * 4) * 64 + h) * 64 + p;
    out[obase]          = sum.x;
    out[obase + 4096]   = sum.y;
    out[obase + 2*4096] = sum.z;
    out[obase + 3*4096] = sum.w;
  }
}

extern "C" void kernel_launch(void* const* d_in, const int* in_sizes, int n_in,
                              void* d_out, int out_size, void* d_ws, size_t ws_size,
                              hipStream_t stream) {
  const float* x       = (const float*)d_in[0];
  const float* filters = (const float*)d_in[1];
  const float* biases  = (const float*)d_in[2];
  float* out = (float*)d_out;
  unsigned short* W2 = (unsigned short*)d_ws;   // 229376 bf16 = 458752 B

  void* args[] = {(void*)&x, (void*)&W2, (void*)&filters, (void*)&biases,
                  (void*)&out};
  hipLaunchCooperativeKernel((const void*)poly2d_fused, dim3(256), dim3(1024),
                             args, 0, stream);
}

// Round 12
// 22.143 us; speedup vs baseline: 5.9596x; 5.9596x over previous
//
#include <hip/hip_runtime.h>
#include <hip/hip_bf16.h>

// Poly2d as fp16 MFMA GEMM, register-resident Q (R9 chassis + f16 path).
// out[o,p] = sum_{c,kl} W[o,c,kl] * Q[c,kl,p], kl in [0,56):
//   kl 0..8 linear (s_j*(F0j+Fj0)), 9..17 squares (s_j^2*Fjj),
//   18..53 pairs (s_i*s_j*(Fij+Fji)), 54 const-1 (F00 + bias @c==0), 55 zero.
// MFMA 32x32x16 B-operand: lane (hf=l>>5, n=l&31) holds B[k=hf*8+e][n].
// k-slot -> (channel,kl) bijection so each lane's slots use only channels
// cA = 2*pair+hf, cB = 2*pair+1-hf with compile-time kl:
//   step st<4 : ch = cA, kl = 16*st + e
//   step st>=4: ch = cB, kl = 16*(st-4)+8+e
// W2 layout: pair*7168 + st*1024 + hf*512 + o*8 + e  (f16 elements).
//
// R12 = R11 with the cvt_pkrtz type error fixed: plain (_Float16) casts
// (compiler emits v_cvt_f16_f32 and SLP-packs f16 muls; m240 says hand-cvt
// is counterproductive). Changes vs R9 (VALU-bound per R10: VALUBusy
// 4.3us/CU vs MfmaUtil 2.8us/CU): (1) products born f16; (2) f16 W2 +
// mfma_f32_32x32x16_f16; (3) reduction arena XOR-swizzle (334K conflicts).

typedef _Float16 half8 __attribute__((ext_vector_type(8)));
typedef __attribute__((ext_vector_type(16))) float f32x16;

#define NCH  64
#define NOUT 64

__device__ constexpr signed char TI[56] = {
  0,0,0,0,0,0,0,0,0,
  1,2,3,4,5,6,7,8,9,
  1,1,1,1,1,1,1,1,
  2,2,2,2,2,2,2,
  3,3,3,3,3,3,
  4,4,4,4,4,
  5,5,5,5,
  6,6,6,
  7,7,
  8,
  0,0};
__device__ constexpr signed char TJ[56] = {
  1,2,3,4,5,6,7,8,9,
  1,2,3,4,5,6,7,8,9,
  2,3,4,5,6,7,8,9,
  3,4,5,6,7,8,9,
  4,5,6,7,8,9,
  5,6,7,8,9,
  6,7,8,9,
  7,8,9,
  8,9,
  9,
  0,0};

__device__ __forceinline__ unsigned short f2h(float f) {
  _Float16 h = (_Float16)f;
  unsigned short u;
  __builtin_memcpy(&u, &h, 2);
  return u;
}

// prep_w2 v3.1 geometry (proven R7-R9), emitting f16.
// 256 blocks = (pair, o-octet). Coalesced float4 stage of F[og*8..+8,
// 2p:2p+2] into LDS, emit 112 half8 contiguous (128B groups).
__global__ __launch_bounds__(256) void prep_w2(const float* __restrict__ F,
                                               const float* __restrict__ biases,
                                               unsigned short* __restrict__ W2) {
  const int pair = blockIdx.x >> 3, og = blockIdx.x & 7;
  __shared__ float Fl[8 * 200];     // [o8][chl*100 + i*10+j]
  __shared__ float bl[8];
  for (int t = threadIdx.x; t < 400; t += 256) {   // 400 float4 = 1600 floats
    int o8 = t / 50, r = t % 50;
    *(float4*)&Fl[o8 * 200 + r * 4] =
        *(const float4*)&F[(((size_t)(og * 8 + o8)) * NCH + 2 * pair) * 100 + r * 4];
  }
  if (threadIdx.x < 8) bl[threadIdx.x] = biases[og * 8 + threadIdx.x];
  __syncthreads();
  {
    int s = threadIdx.x;
    if (s < 112) {                  // o8 fast -> 8 consecutive half8 = 128B
      int o8 = s & 7, hf = (s >> 3) & 1, st = s >> 4;
      int chl = (st < 4) ? hf : 1 - hf;
      const float* base = &Fl[o8 * 200 + chl * 100];
      unsigned short v[8];
      #pragma unroll
      for (int e = 0; e < 8; ++e) {
        int kl = (st < 4) ? (16 * st + e) : (16 * (st - 4) + 8 + e);
        float w;
        if (kl < 54) {
          int i = TI[kl], j = TJ[kl];
          if (i == 0)      w = base[j] + base[j * 10];
          else if (i == j) w = base[i * 10 + j];
          else             w = base[i * 10 + j] + base[j * 10 + i];
        } else if (kl == 54) {
          w = base[0] + ((pair == 0 && chl == 0) ? bl[o8] : 0.f);
        } else {
          w = 0.f;
        }
        v[e] = f2h(w);
      }
      *(uint4*)&W2[(size_t)pair * 7168 + (size_t)st * 1024 + hf * 512 +
                   (og * 8 + o8) * 8] = *(const uint4*)v;
    }
  }
}

// 256 blocks = (b, h); 1024 threads = 16 waves = (kg 0..7, ph 0..1).
// Wave (kg,ph): channels [8kg, 8kg+8), pixels [32ph, 32ph+32), o 0..63
// (2 acc tiles). LDS arena 139 KB (xs 55 KB / reduction 139 KB, aliased):
// 1 block/CU, 4 waves/SIMD at <=128 VGPR.
//   xs: channel ci -> dwords [ci*216, +216): 3 rows x 72 cols, x[w] at col
//       w+4, cols 0..3 / 68..71 zero halo.
//   R:  partials, row (kg*64+p) stride 68 dwords, o-offset XOR-swizzled
//       by ((row&7)<<3) (both sides) -> <=2-way banks (free, m136).
__global__ __launch_bounds__(1024, 4) void poly2d_mfma(
    const float* __restrict__ x, const unsigned short* __restrict__ W2,
    float* __restrict__ out) {
  const int b = blockIdx.x >> 6, h = blockIdx.x & 63;
  const int tid = threadIdx.x;
  const int lane = tid & 63, wid = tid >> 6;
  const int kg = wid >> 1, ph = wid & 1;
  const int px = lane & 31, hf = lane >> 5;
  const int pxa = ph * 32 + px;            // this wave's absolute pixel

  __shared__ float smem[34816];   // 139264 B

  // ---- stage: wave wid stages channels [4*wid, 4*wid+4) ----
  {
    const int r = lane >> 4, q = lane & 15;          // lanes 0..47: body quads
    const size_t xbase = ((size_t)b * NCH + wid * 4) * 4096;
    #pragma unroll
    for (int i = 0; i < 4; ++i) {
      float* ch0 = &smem[(wid * 4 + i) * 216];
      if (lane < 48) {
        int hh = h + r - 1;
        bool ok = (unsigned)hh < 64u;
        int hcl = ok ? hh : 0;                       // clamped (safe) address
        float4 v = *(const float4*)&x[xbase + (size_t)i * 4096 + hcl * 64 + (q << 2)];
        if (!ok) v = make_float4(0.f, 0.f, 0.f, 0.f);
        *(float4*)&ch0[r * 72 + 4 + (q << 2)] = v;
      } else if (lane < 54) {
        int rr = (lane - 48) >> 1, side = lane & 1;  // zero halo cols
        *(float4*)&ch0[rr * 72 + (side ? 68 : 0)] = make_float4(0.f, 0.f, 0.f, 0.f);
      }
    }
  }
  __syncthreads();                 // staging shared across waves

  f32x16 acc0, acc1;               // o 0..31 / o 32..63 at this wave's px
  #pragma unroll
  for (int r = 0; r < 16; ++r) { acc0[r] = 0.f; acc1[r] = 0.f; }

  #pragma unroll
  for (int stage = 0; stage < 4; ++stage) {
    const int cA = kg * 8 + stage * 2 + hf;   // channel of this lane-half
    const int cB = cA ^ 1;

    const float* rA = &smem[cA * 216 + pxa];
    const float* rB = &smem[cB * 216 + pxa];
    float sa[9], sb[9];
    #pragma unroll
    for (int r = 0; r < 3; ++r)
      #pragma unroll
      for (int d = 0; d < 3; ++d) {
        sa[r * 3 + d] = rA[r * 72 + 3 + d];
        sb[r * 3 + d] = rB[r * 72 + 3 + d];
      }

    // ---- convert windows to f16 once (compiler packs cvt + pk_mul) ----
    _Float16 shA[9], shB[9];
    #pragma unroll
    for (int k = 0; k < 9; ++k) {
      shA[k] = (_Float16)sa[k];
      shB[k] = (_Float16)sb[k];
    }

    const unsigned short* wb = W2 + (size_t)(kg * 4 + stage) * 7168 +
                               hf * 512 + px * 8;
    #pragma unroll
    for (int st = 0; st < 7; ++st) {
      const half8 w0 = *(const half8*)(wb + st * 1024);        // o 0..31
      const half8 w1 = *(const half8*)(wb + st * 1024 + 256);  // o 32..63
      half8 pk;
      #pragma unroll
      for (int e = 0; e < 8; ++e) {
        const int kl = (st < 4) ? (16 * st + e) : (16 * (st - 4) + 8 + e);
        const _Float16* s = (st < 4) ? shA : shB;
        _Float16 v;
        if (kl == 55)      v = (_Float16)0.f;
        else if (kl == 54) v = (_Float16)1.f;
        else if (kl < 9)   v = s[kl];
        else if (kl < 18)  { _Float16 t = s[kl - 9]; v = t * t; }
        else               v = s[TI[kl] - 1] * s[TJ[kl] - 1];
        pk[e] = v;
      }
      acc0 = __builtin_amdgcn_mfma_f32_32x32x16_f16(w0, pk, acc0, 0, 0, 0);
      acc1 = __builtin_amdgcn_mfma_f32_32x32x16_f16(w1, pk, acc1, 0, 0, 0);
    }
  }

  // ---- single-round reduction over the 8 kg partials (XOR-swizzled) ----
  __syncthreads();               // all waves done with xs (arena reused as R)
  // D layout (m74/m101): col = lane&31 (= pixel), row = (r&3)+8*(r>>2)+4*hf
  // (= o_local). R(kg, p, o) at smem[(kg*64+p)*68 + (o4 ^ ((p&7)<<3))].
  {
    float* base = &smem[(kg * 64 + pxa) * 68];
    const int key = (pxa & 7) << 3;
    #pragma unroll
    for (int blk = 0; blk < 4; ++blk) {
      int ob = blk * 8 + 4 * hf;
      *(float4*)&base[ob ^ key] =
          make_float4(acc0[blk*4], acc0[blk*4+1], acc0[blk*4+2], acc0[blk*4+3]);
      *(float4*)&base[(ob + 32) ^ key] =
          make_float4(acc1[blk*4], acc1[blk*4+1], acc1[blk*4+2], acc1[blk*4+3]);
    }
  }
  __syncthreads();
  {
    const int p = tid & 63, oq = tid >> 6;   // o-quad 0..15
    const int key = (p & 7) << 3;
    float4 sum = make_float4(0.f, 0.f, 0.f, 0.f);
    #pragma unroll
    for (int g = 0; g < 8; ++g) {
      float4 v = *(const float4*)&smem[(g * 64 + p) * 68 + ((oq * 4) ^ key)];
      sum.x += v.x; sum.y += v.y; sum.z += v.z; sum.w += v.w;
    }
    const size_t obase = (((size_t)b * NOUT + oq * 4) * 64 + h) * 64 + p;
    out[obase]          = sum.x;
    out[obase + 4096]   = sum.y;
    out[obase + 2*4096] = sum.z;
    out[obase + 3*4096] = sum.w;
  }
}

extern "C" void kernel_launch(void* const* d_in, const int* in_sizes, int n_in,
                              void* d_out, int out_size, void* d_ws, size_t ws_size,
                              hipStream_t stream) {
  const float* x       = (const float*)d_in[0];
  const float* filters = (const float*)d_in[1];
  const float* biases  = (const float*)d_in[2];
  float* out = (float*)d_out;
  unsigned short* W2 = (unsigned short*)d_ws;   // 229376 f16 = 458752 B

  hipLaunchKernelGGL(prep_w2, dim3(256), dim3(256), 0, stream,
                     filters, biases, W2);
  hipLaunchKernelGGL(poly2d_mfma, dim3(256), dim3(1024), 0, stream,
                     x, W2, out);
}